// Round 6
// baseline (20901.961 us; speedup 1.0000x reference)
//
#include <hip/hip_runtime.h>
#include <cstdint>

#define NB 128
#define NT 512
#define NL 512
#define NH 512
#define NU 512

// 2*log2(e): tanh(x) = 1 - 2/(exp2(K2E*x)+1); exp2 hoisted into the GEMM epilogue.
static constexpr float K2E = 2.8853900817779268f;

// ---------------------------------------------------------------- K0: sum(V)+bV
__global__ __launch_bounds__(256) void k_sumv(const float* __restrict__ V,
                                              const float* __restrict__ bV,
                                              float* __restrict__ svbv) {
  __shared__ float red[256];
  int tid = threadIdx.x;
  red[tid] = V[tid] + V[tid + 256];
  __syncthreads();
  for (int off = 128; off > 0; off >>= 1) {
    if (tid < off) red[tid] += red[tid + off];
    __syncthreads();
  }
  if (tid == 0) svbv[0] = red[0] + bV[0];
}

// --------------------------------------- K1/K2: out = exp2(K2E*(A@W + bias))
__global__ __launch_bounds__(256) void k_proj_exp(const float* __restrict__ A,
                                                  const float* __restrict__ W,
                                                  const float* __restrict__ bias,
                                                  float* __restrict__ out) {
  __shared__ float As[128 * 32];   // swizzled 16B granules, row stride 128B
  __shared__ float Ws[32 * 132];   // padded stride 132 floats
  const int tid = threadIdx.x;
  const int m0 = blockIdx.y * 128;
  const int n0 = blockIdx.x * 128;
  const int i = tid & 15;
  const int j = tid >> 4;
  const int ga = tid & 7, mra = tid >> 3;
  const int gw = tid & 31, kw = tid >> 5;

  float acc[8][8];
#pragma unroll
  for (int a = 0; a < 8; ++a)
#pragma unroll
    for (int b = 0; b < 8; ++b) acc[a][b] = 0.f;

  for (int kc = 0; kc < NH; kc += 32) {
#pragma unroll
    for (int q = 0; q < 4; ++q) {
      int row = mra + 32 * q;
      float4 av = *(const float4*)(A + (size_t)(m0 + row) * NH + kc + 4 * ga);
      int pos = ga ^ ((row ^ (row >> 3)) & 7);
      *(float4*)(As + row * 32 + 4 * pos) = av;
    }
#pragma unroll
    for (int q = 0; q < 4; ++q) {
      int row = kw + 8 * q;
      float4 wv = *(const float4*)(W + (size_t)(kc + row) * NU + n0 + 4 * gw);
      *(float4*)(Ws + row * 132 + 4 * gw) = wv;
    }
    __syncthreads();
#pragma unroll
    for (int k4 = 0; k4 < 32; k4 += 4) {
      const int gk = k4 >> 2;
      float4 a4[8];
      float4 bl[4], bh[4];
#pragma unroll
      for (int r = 0; r < 8; ++r) {
        int row = 8 * i + r;
        a4[r] = *(const float4*)(As + row * 32 + 4 * (gk ^ ((row ^ (row >> 3)) & 7)));
      }
#pragma unroll
      for (int r = 0; r < 4; ++r) {
        bl[r] = *(const float4*)(Ws + (k4 + r) * 132 + 8 * j);
        bh[r] = *(const float4*)(Ws + (k4 + r) * 132 + 8 * j + 4);
      }
#pragma unroll
      for (int r = 0; r < 4; ++r) {
        float bv[8] = {bl[r].x, bl[r].y, bl[r].z, bl[r].w,
                       bh[r].x, bh[r].y, bh[r].z, bh[r].w};
#pragma unroll
        for (int a = 0; a < 8; ++a) {
          float av = ((const float*)&a4[a])[r];
#pragma unroll
          for (int b = 0; b < 8; ++b) acc[a][b] = fmaf(av, bv[b], acc[a][b]);
        }
      }
    }
    __syncthreads();
  }
#pragma unroll
  for (int a = 0; a < 8; ++a) {
    size_t orow = (size_t)(m0 + 8 * i + a) * NU + n0 + 8 * j;
#pragma unroll
    for (int b = 0; b < 8; b += 4) {
      float4 ov;
      ov.x = __builtin_amdgcn_exp2f(K2E * (acc[a][b + 0] + bias[n0 + 8 * j + b + 0]));
      ov.y = __builtin_amdgcn_exp2f(K2E * (acc[a][b + 1] + bias[n0 + 8 * j + b + 1]));
      ov.z = __builtin_amdgcn_exp2f(K2E * (acc[a][b + 2] + bias[n0 + 8 * j + b + 2]));
      ov.w = __builtin_amdgcn_exp2f(K2E * (acc[a][b + 3] + bias[n0 + 8 * j + b + 3]));
      *(float4*)(out + orow + b) = ov;
    }
  }
}

// ---------------------------------------------- K3: S[b,t,l] = base - 2*sum_u V*rc
// Scalar octet fraction-merge tree (31 VALU + 1 rcp per 8 elems). Occupancy
// round: single-buffered 16.4KB LDS, V via wave-uniform scalar loads (SGPR
// operand slot), __launch_bounds__(256,4) caps VGPR at 128 -> 4 waves/SIMD.
__global__ __launch_bounds__(256, 4) void k_score(const float* __restrict__ Ed,
                                                  const float* __restrict__ Ee,
                                                  const float* __restrict__ Vv,
                                                  const float* __restrict__ svbv,
                                                  float* __restrict__ out) {
  __shared__ float dpl[64 * 32];   // 8 KB, swizzled 16B granules
  __shared__ float epl[64 * 32];   // 8 KB, swizzled
  const int tid = threadIdx.x;
  const int b = blockIdx.z;
  const int t0 = blockIdx.y * 64;
  const int l0 = blockIdx.x * 64;
  const int ti = tid & 15;          // t micro group (4 rows)
  const int lj = tid >> 4;          // l micro group (4 cols)
  const int tt = tid & 63;          // staging row
  const int g0 = (tid >> 6) * 2;    // staging granules g0, g0+1
  const float* Edb = Ed + ((size_t)b * NT + t0) * NU;
  const float* Eeb = Ee + ((size_t)b * NL + l0) * NU;
  const int sw = (tt ^ (tt >> 3)) & 7;
  const int pos0 = tt * 32 + 4 * ((g0 + 0) ^ sw);
  const int pos1 = tt * 32 + 4 * ((g0 + 1) ^ sw);
  const size_t srow = (size_t)tt * NU;

  float acc[4][4];
#pragma unroll
  for (int a = 0; a < 4; ++a)
#pragma unroll
    for (int c = 0; c < 4; ++c) acc[a][c] = 0.f;

  // prologue: stage chunk 0
  {
    float4 d0 = *(const float4*)(Edb + srow + 4 * g0);
    float4 d1 = *(const float4*)(Edb + srow + 4 * g0 + 4);
    float4 e0 = *(const float4*)(Eeb + srow + 4 * g0);
    float4 e1 = *(const float4*)(Eeb + srow + 4 * g0 + 4);
    *(float4*)(dpl + pos0) = d0;
    *(float4*)(dpl + pos1) = d1;
    *(float4*)(epl + pos0) = e0;
    *(float4*)(epl + pos1) = e1;
  }
  __syncthreads();

#pragma unroll 1
  for (int c = 0; c < 16; ++c) {
    // issue next-chunk global loads first (latency hidden under compute)
    float4 pd0, pd1, pe0, pe1;
    if (c < 15) {
      const int uc = (c + 1) * 32;
      pd0 = *(const float4*)(Edb + srow + uc + 4 * g0);
      pd1 = *(const float4*)(Edb + srow + uc + 4 * g0 + 4);
      pe0 = *(const float4*)(Eeb + srow + uc + 4 * g0);
      pe1 = *(const float4*)(Eeb + srow + uc + 4 * g0 + 4);
    }
#pragma unroll
    for (int g8 = 0; g8 < 4; ++g8) {
      float4 aLo[4], aHi[4], bLo[4], bHi[4];
#pragma unroll
      for (int r = 0; r < 4; ++r) {
        int rowa = 4 * ti + r;
        int swa = (rowa ^ (rowa >> 3)) & 7;
        aLo[r] = *(const float4*)(dpl + rowa * 32 + 4 * ((2 * g8 + 0) ^ swa));
        aHi[r] = *(const float4*)(dpl + rowa * 32 + 4 * ((2 * g8 + 1) ^ swa));
        int rowb = 4 * lj + r;
        int swb = (rowb ^ (rowb >> 3)) & 7;
        bLo[r] = *(const float4*)(epl + rowb * 32 + 4 * ((2 * g8 + 0) ^ swb));
        bHi[r] = *(const float4*)(epl + rowb * 32 + 4 * ((2 * g8 + 1) ^ swb));
      }
      // wave-uniform V loads -> scalar (SGPR) loads, free VALU operand slot
      const float* vb = Vv + c * 32 + g8 * 8;
      const float v0 = vb[0], v1 = vb[1], v2 = vb[2], v3 = vb[3];
      const float v4_ = vb[4], v5 = vb[5], v6 = vb[6], v7 = vb[7];
#pragma unroll
      for (int a = 0; a < 4; ++a) {
        const float* ap = (const float*)&aLo[a];
        const float* ah = (const float*)&aHi[a];
#pragma unroll
        for (int cc = 0; cc < 4; ++cc) {
          const float* bp = (const float*)&bLo[cc];
          const float* bh = (const float*)&bHi[cc];
          float d0 = fmaf(ap[0], bp[0], 1.0f);
          float d1 = fmaf(ap[1], bp[1], 1.0f);
          float d2 = fmaf(ap[2], bp[2], 1.0f);
          float d3 = fmaf(ap[3], bp[3], 1.0f);
          float d4 = fmaf(ah[0], bh[0], 1.0f);
          float d5 = fmaf(ah[1], bh[1], 1.0f);
          float d6 = fmaf(ah[2], bh[2], 1.0f);
          float d7 = fmaf(ah[3], bh[3], 1.0f);
          float d01 = d0 * d1, d23 = d2 * d3, d45 = d4 * d5, d67 = d6 * d7;
          float n01 = fmaf(v0, d1, v1 * d0);
          float n23 = fmaf(v2, d3, v3 * d2);
          float n45 = fmaf(v4_, d5, v5 * d4);
          float n67 = fmaf(v6, d7, v7 * d6);
          float n03 = fmaf(n01, d23, n23 * d01);
          float d03 = d01 * d23;
          float n47 = fmaf(n45, d67, n67 * d45);
          float d47 = d45 * d67;
          float num = fmaf(n03, d47, n47 * d03);
          float den = d03 * d47;
          acc[a][cc] = fmaf(num, __builtin_amdgcn_rcpf(den), acc[a][cc]);
        }
      }
    }
    __syncthreads();   // all reads of this chunk done (uniform)
    if (c < 15) {
      *(float4*)(dpl + pos0) = pd0;
      *(float4*)(dpl + pos1) = pd1;
      *(float4*)(epl + pos0) = pe0;
      *(float4*)(epl + pos1) = pe1;
      __syncthreads(); // writes visible (uniform)
    }
  }

  const float base = svbv[0];  // sum(V) + bV
#pragma unroll
  for (int a = 0; a < 4; ++a) {
    size_t orow = ((size_t)b * NT + t0 + 4 * ti + a) * NL + l0 + 4 * lj;
    float4 ov;
    ov.x = base - 2.f * acc[a][0];
    ov.y = base - 2.f * acc[a][1];
    ov.z = base - 2.f * acc[a][2];
    ov.w = base - 2.f * acc[a][3];
    *(float4*)(out + orow) = ov;
  }
}

// ------------------------- K4: sequential mask/softmax/argmax, in-place on d_out
__global__ __launch_bounds__(64) void k_seq(float* __restrict__ out) {
  const int b = blockIdx.x;
  const int lane = threadIdx.x;
  float* base = out + (size_t)b * NT * NL;
  float maskf[8];
#pragma unroll
  for (int k = 0; k < 8; ++k) maskf[k] = 0.f;
  float cur[8];
#pragma unroll
  for (int k = 0; k < 8; ++k) cur[k] = base[lane + 64 * k];

  for (int t = 0; t < NT; ++t) {
    float nxt[8] = {0.f, 0.f, 0.f, 0.f, 0.f, 0.f, 0.f, 0.f};
    if (t + 1 < NT) {
      const float* nr = base + (size_t)(t + 1) * NL;
#pragma unroll
      for (int k = 0; k < 8; ++k) nxt[k] = nr[lane + 64 * k];
    }
    float v[8];
    float mval = -3.4e38f;
    int midx = 0x7fffffff;
#pragma unroll
    for (int k = 0; k < 8; ++k) {
      v[k] = cur[k] - maskf[k] * 1000000.0f;
      int idx = lane + 64 * k;
      if (v[k] > mval || (v[k] == mval && idx < midx)) { mval = v[k]; midx = idx; }
    }
#pragma unroll
    for (int off = 32; off > 0; off >>= 1) {
      float ov = __shfl_xor(mval, off);
      int oi = __shfl_xor(midx, off);
      if (ov > mval || (ov == mval && oi < midx)) { mval = ov; midx = oi; }
    }
    float p[8];
    float psum = 0.f;
#pragma unroll
    for (int k = 0; k < 8; ++k) { p[k] = __expf(v[k] - mval); psum += p[k]; }
#pragma unroll
    for (int off = 32; off > 0; off >>= 1) psum += __shfl_xor(psum, off);
    const float inv = 1.0f / psum;
    float* orow = base + (size_t)t * NL;
#pragma unroll
    for (int k = 0; k < 8; ++k) orow[lane + 64 * k] = p[k] * inv;
#pragma unroll
    for (int k = 0; k < 8; ++k)
      if (lane + 64 * k == midx) maskf[k] += 1.0f;
#pragma unroll
    for (int k = 0; k < 8; ++k) cur[k] = nxt[k];
  }
}

extern "C" void kernel_launch(void* const* d_in, const int* in_sizes, int n_in,
                              void* d_out, int out_size, void* d_ws, size_t ws_size,
                              hipStream_t stream) {
  const float* dec_outputs = (const float*)d_in[0];  // [B,T,H]
  const float* enc_outputs = (const float*)d_in[1];  // [B,L,H]
  const float* W1 = (const float*)d_in[3];
  const float* b1 = (const float*)d_in[4];
  const float* W2 = (const float*)d_in[5];
  const float* b2 = (const float*)d_in[6];
  const float* V  = (const float*)d_in[7];
  const float* bV = (const float*)d_in[8];
  float* out = (float*)d_out;  // [B,T,L] f32

  // workspace: [svbv pad 256B][Ed 134MB][Ee 134MB]
  float* svbv = (float*)d_ws;
  float* Ed = (float*)((char*)d_ws + 256);
  float* Ee = Ed + (size_t)NB * NT * NU;

  hipLaunchKernelGGL(k_sumv, dim3(1), dim3(256), 0, stream, V, bV, svbv);
  hipLaunchKernelGGL(k_proj_exp, dim3(NU / 128, (NB * NT) / 128), dim3(256), 0, stream,
                     dec_outputs, W1, b1, Ed);
  hipLaunchKernelGGL(k_proj_exp, dim3(NU / 128, (NB * NL) / 128), dim3(256), 0, stream,
                     enc_outputs, W2, b2, Ee);
  hipLaunchKernelGGL(k_score, dim3(NL / 64, NT / 64, NB), dim3(256), 0, stream,
                     Ed, Ee, V, svbv, out);
  hipLaunchKernelGGL(k_seq, dim3(NB), dim3(64), 0, stream, out);
}

// Round 7
// 10746.847 us; speedup vs baseline: 1.9449x; 1.9449x over previous
//
#include <hip/hip_runtime.h>
#include <cstdint>

#define NB 128
#define NT 512
#define NL 512
#define NH 512
#define NU 512

// 2*log2(e): tanh(x) = 1 - 2/(exp2(K2E*x)+1); exp2 hoisted into the GEMM epilogue.
static constexpr float K2E = 2.8853900817779268f;

// ---------------------------------------------------------------- K0: sum(V)+bV
__global__ __launch_bounds__(256) void k_sumv(const float* __restrict__ V,
                                              const float* __restrict__ bV,
                                              float* __restrict__ svbv) {
  __shared__ float red[256];
  int tid = threadIdx.x;
  red[tid] = V[tid] + V[tid + 256];
  __syncthreads();
  for (int off = 128; off > 0; off >>= 1) {
    if (tid < off) red[tid] += red[tid + off];
    __syncthreads();
  }
  if (tid == 0) svbv[0] = red[0] + bV[0];
}

// --------------------------------------- K1/K2: out = exp2(K2E*(A@W + bias))
__global__ __launch_bounds__(256) void k_proj_exp(const float* __restrict__ A,
                                                  const float* __restrict__ W,
                                                  const float* __restrict__ bias,
                                                  float* __restrict__ out) {
  __shared__ float As[128 * 32];   // swizzled 16B granules, row stride 128B
  __shared__ float Ws[32 * 132];   // padded stride 132 floats
  const int tid = threadIdx.x;
  const int m0 = blockIdx.y * 128;
  const int n0 = blockIdx.x * 128;
  const int i = tid & 15;
  const int j = tid >> 4;
  const int ga = tid & 7, mra = tid >> 3;
  const int gw = tid & 31, kw = tid >> 5;

  float acc[8][8];
#pragma unroll
  for (int a = 0; a < 8; ++a)
#pragma unroll
    for (int b = 0; b < 8; ++b) acc[a][b] = 0.f;

  for (int kc = 0; kc < NH; kc += 32) {
#pragma unroll
    for (int q = 0; q < 4; ++q) {
      int row = mra + 32 * q;
      float4 av = *(const float4*)(A + (size_t)(m0 + row) * NH + kc + 4 * ga);
      int pos = ga ^ ((row ^ (row >> 3)) & 7);
      *(float4*)(As + row * 32 + 4 * pos) = av;
    }
#pragma unroll
    for (int q = 0; q < 4; ++q) {
      int row = kw + 8 * q;
      float4 wv = *(const float4*)(W + (size_t)(kc + row) * NU + n0 + 4 * gw);
      *(float4*)(Ws + row * 132 + 4 * gw) = wv;
    }
    __syncthreads();
#pragma unroll
    for (int k4 = 0; k4 < 32; k4 += 4) {
      const int gk = k4 >> 2;
      float4 a4[8];
      float4 bl[4], bh[4];
#pragma unroll
      for (int r = 0; r < 8; ++r) {
        int row = 8 * i + r;
        a4[r] = *(const float4*)(As + row * 32 + 4 * (gk ^ ((row ^ (row >> 3)) & 7)));
      }
#pragma unroll
      for (int r = 0; r < 4; ++r) {
        bl[r] = *(const float4*)(Ws + (k4 + r) * 132 + 8 * j);
        bh[r] = *(const float4*)(Ws + (k4 + r) * 132 + 8 * j + 4);
      }
#pragma unroll
      for (int r = 0; r < 4; ++r) {
        float bv[8] = {bl[r].x, bl[r].y, bl[r].z, bl[r].w,
                       bh[r].x, bh[r].y, bh[r].z, bh[r].w};
#pragma unroll
        for (int a = 0; a < 8; ++a) {
          float av = ((const float*)&a4[a])[r];
#pragma unroll
          for (int b = 0; b < 8; ++b) acc[a][b] = fmaf(av, bv[b], acc[a][b]);
        }
      }
    }
    __syncthreads();
  }
#pragma unroll
  for (int a = 0; a < 8; ++a) {
    size_t orow = (size_t)(m0 + 8 * i + a) * NU + n0 + 8 * j;
#pragma unroll
    for (int b = 0; b < 8; b += 4) {
      float4 ov;
      ov.x = __builtin_amdgcn_exp2f(K2E * (acc[a][b + 0] + bias[n0 + 8 * j + b + 0]));
      ov.y = __builtin_amdgcn_exp2f(K2E * (acc[a][b + 1] + bias[n0 + 8 * j + b + 1]));
      ov.z = __builtin_amdgcn_exp2f(K2E * (acc[a][b + 2] + bias[n0 + 8 * j + b + 2]));
      ov.w = __builtin_amdgcn_exp2f(K2E * (acc[a][b + 3] + bias[n0 + 8 * j + b + 3]));
      *(float4*)(out + orow + b) = ov;
    }
  }
}

// ---------------------------------------------- K3: S[b,t,l] = base - 2*sum_u V*rc
// Single-wave blocks (64 thr), 32x32 tile, 4x4 micro, ZERO barriers: the wave
// reads its own LDS writes (per-wave DS ops are in-order; lgkmcnt covers data).
// Octet fraction-merge tree (31 VALU + 1 rcp per 8 elems) -- same math as R5/R6.
// launch_bounds(64,3): VGPR cap 170 >= ~140 live -> no spill (R6 lesson).
__global__ __launch_bounds__(64, 3) void k_score(const float* __restrict__ Ed,
                                                 const float* __restrict__ Ee,
                                                 const float* __restrict__ Vv,
                                                 const float* __restrict__ svbv,
                                                 float* __restrict__ out) {
  __shared__ float dpl[2][32 * 32];   // 2 x 4 KB, swizzled 16B granules
  __shared__ float epl[2][32 * 32];   // 2 x 4 KB
  const int tid = threadIdx.x;         // 0..63, one wave
  const int b = blockIdx.z;
  const int t0 = blockIdx.y * 32;
  const int l0 = blockIdx.x * 32;
  const int ti = tid & 7;              // t micro group (4 rows)
  const int lj = tid >> 3;             // l micro group (4 cols)
  // staging: row = tid>>1 (32 rows), granule base (tid&1)*4 (granules 0-3 / 4-7)
  const int srow_i = tid >> 1;
  const int gbase = (tid & 1) * 4;
  const int ssw = (srow_i ^ (srow_i >> 3)) & 7;
  const float* Edb = Ed + ((size_t)b * NT + t0) * NU;
  const float* Eeb = Ee + ((size_t)b * NL + l0) * NU;
  const size_t srow = (size_t)srow_i * NU;
  int wpos[4];
#pragma unroll
  for (int q = 0; q < 4; ++q) wpos[q] = srow_i * 32 + 4 * ((gbase + q) ^ ssw);

  float acc[4][4];
#pragma unroll
  for (int a = 0; a < 4; ++a)
#pragma unroll
    for (int c = 0; c < 4; ++c) acc[a][c] = 0.f;

  // prologue: stage chunk 0 into buffer 0 (no barrier: same-wave RAW via lgkmcnt)
  {
    float4 pa[4], pb[4];
#pragma unroll
    for (int q = 0; q < 4; ++q) {
      pa[q] = *(const float4*)(Edb + srow + 4 * (gbase + q));
      pb[q] = *(const float4*)(Eeb + srow + 4 * (gbase + q));
    }
#pragma unroll
    for (int q = 0; q < 4; ++q) {
      *(float4*)(dpl[0] + wpos[q]) = pa[q];
      *(float4*)(epl[0] + wpos[q]) = pb[q];
    }
  }

#pragma unroll 1
  for (int c = 0; c < 16; ++c) {
    const float* dbuf = dpl[c & 1];
    const float* ebuf = epl[c & 1];
    // issue next-chunk global loads (latency hides under this chunk's compute)
    float4 pa[4], pb[4];
    if (c < 15) {
      const int uc = (c + 1) * 32;
#pragma unroll
      for (int q = 0; q < 4; ++q) {
        pa[q] = *(const float4*)(Edb + srow + uc + 4 * (gbase + q));
        pb[q] = *(const float4*)(Eeb + srow + uc + 4 * (gbase + q));
      }
    }
#pragma unroll
    for (int g8 = 0; g8 < 4; ++g8) {
      float4 aLo[4], aHi[4], bLo[4], bHi[4];
#pragma unroll
      for (int r = 0; r < 4; ++r) {
        int rowa = 4 * ti + r;
        int swa = (rowa ^ (rowa >> 3)) & 7;
        aLo[r] = *(const float4*)(dbuf + rowa * 32 + 4 * ((2 * g8 + 0) ^ swa));
        aHi[r] = *(const float4*)(dbuf + rowa * 32 + 4 * ((2 * g8 + 1) ^ swa));
        int rowb = 4 * lj + r;
        int swb = (rowb ^ (rowb >> 3)) & 7;
        bLo[r] = *(const float4*)(ebuf + rowb * 32 + 4 * ((2 * g8 + 0) ^ swb));
        bHi[r] = *(const float4*)(ebuf + rowb * 32 + 4 * ((2 * g8 + 1) ^ swb));
      }
      // wave-uniform V loads -> scalar loads (SGPR operands)
      const float* vb = Vv + c * 32 + g8 * 8;
      const float v0 = vb[0], v1 = vb[1], v2 = vb[2], v3 = vb[3];
      const float v4_ = vb[4], v5 = vb[5], v6 = vb[6], v7 = vb[7];
#pragma unroll
      for (int a = 0; a < 4; ++a) {
        const float* ap = (const float*)&aLo[a];
        const float* ah = (const float*)&aHi[a];
#pragma unroll
        for (int cc = 0; cc < 4; ++cc) {
          const float* bp = (const float*)&bLo[cc];
          const float* bh = (const float*)&bHi[cc];
          float d0 = fmaf(ap[0], bp[0], 1.0f);
          float d1 = fmaf(ap[1], bp[1], 1.0f);
          float d2 = fmaf(ap[2], bp[2], 1.0f);
          float d3 = fmaf(ap[3], bp[3], 1.0f);
          float d4 = fmaf(ah[0], bh[0], 1.0f);
          float d5 = fmaf(ah[1], bh[1], 1.0f);
          float d6 = fmaf(ah[2], bh[2], 1.0f);
          float d7 = fmaf(ah[3], bh[3], 1.0f);
          float d01 = d0 * d1, d23 = d2 * d3, d45 = d4 * d5, d67 = d6 * d7;
          float n01 = fmaf(v0, d1, v1 * d0);
          float n23 = fmaf(v2, d3, v3 * d2);
          float n45 = fmaf(v4_, d5, v5 * d4);
          float n67 = fmaf(v6, d7, v7 * d6);
          float n03 = fmaf(n01, d23, n23 * d01);
          float d03 = d01 * d23;
          float n47 = fmaf(n45, d67, n67 * d45);
          float d47 = d45 * d67;
          float num = fmaf(n03, d47, n47 * d03);
          float den = d03 * d47;
          acc[a][cc] = fmaf(num, __builtin_amdgcn_rcpf(den), acc[a][cc]);
        }
      }
    }
    // write chunk c+1 into the other buffer (its reads finished in iter c-1;
    // same-wave program order makes this safe without any barrier)
    if (c < 15) {
      float* dn = dpl[(c + 1) & 1];
      float* en = epl[(c + 1) & 1];
#pragma unroll
      for (int q = 0; q < 4; ++q) {
        *(float4*)(dn + wpos[q]) = pa[q];
        *(float4*)(en + wpos[q]) = pb[q];
      }
    }
  }

  const float base = svbv[0];  // sum(V) + bV
#pragma unroll
  for (int a = 0; a < 4; ++a) {
    size_t orow = ((size_t)b * NT + t0 + 4 * ti + a) * NL + l0 + 4 * lj;
    float4 ov;
    ov.x = base - 2.f * acc[a][0];
    ov.y = base - 2.f * acc[a][1];
    ov.z = base - 2.f * acc[a][2];
    ov.w = base - 2.f * acc[a][3];
    *(float4*)(out + orow) = ov;
  }
}

// ------------------------- K4: sequential mask/softmax/argmax, in-place on d_out
__global__ __launch_bounds__(64) void k_seq(float* __restrict__ out) {
  const int b = blockIdx.x;
  const int lane = threadIdx.x;
  float* base = out + (size_t)b * NT * NL;
  float maskf[8];
#pragma unroll
  for (int k = 0; k < 8; ++k) maskf[k] = 0.f;
  float cur[8];
#pragma unroll
  for (int k = 0; k < 8; ++k) cur[k] = base[lane + 64 * k];

  for (int t = 0; t < NT; ++t) {
    float nxt[8] = {0.f, 0.f, 0.f, 0.f, 0.f, 0.f, 0.f, 0.f};
    if (t + 1 < NT) {
      const float* nr = base + (size_t)(t + 1) * NL;
#pragma unroll
      for (int k = 0; k < 8; ++k) nxt[k] = nr[lane + 64 * k];
    }
    float v[8];
    float mval = -3.4e38f;
    int midx = 0x7fffffff;
#pragma unroll
    for (int k = 0; k < 8; ++k) {
      v[k] = cur[k] - maskf[k] * 1000000.0f;
      int idx = lane + 64 * k;
      if (v[k] > mval || (v[k] == mval && idx < midx)) { mval = v[k]; midx = idx; }
    }
#pragma unroll
    for (int off = 32; off > 0; off >>= 1) {
      float ov = __shfl_xor(mval, off);
      int oi = __shfl_xor(midx, off);
      if (ov > mval || (ov == mval && oi < midx)) { mval = ov; midx = oi; }
    }
    float p[8];
    float psum = 0.f;
#pragma unroll
    for (int k = 0; k < 8; ++k) { p[k] = __expf(v[k] - mval); psum += p[k]; }
#pragma unroll
    for (int off = 32; off > 0; off >>= 1) psum += __shfl_xor(psum, off);
    const float inv = 1.0f / psum;
    float* orow = base + (size_t)t * NL;
#pragma unroll
    for (int k = 0; k < 8; ++k) orow[lane + 64 * k] = p[k] * inv;
#pragma unroll
    for (int k = 0; k < 8; ++k)
      if (lane + 64 * k == midx) maskf[k] += 1.0f;
#pragma unroll
    for (int k = 0; k < 8; ++k) cur[k] = nxt[k];
  }
}

extern "C" void kernel_launch(void* const* d_in, const int* in_sizes, int n_in,
                              void* d_out, int out_size, void* d_ws, size_t ws_size,
                              hipStream_t stream) {
  const float* dec_outputs = (const float*)d_in[0];  // [B,T,H]
  const float* enc_outputs = (const float*)d_in[1];  // [B,L,H]
  const float* W1 = (const float*)d_in[3];
  const float* b1 = (const float*)d_in[4];
  const float* W2 = (const float*)d_in[5];
  const float* b2 = (const float*)d_in[6];
  const float* V  = (const float*)d_in[7];
  const float* bV = (const float*)d_in[8];
  float* out = (float*)d_out;  // [B,T,L] f32

  // workspace: [svbv pad 256B][Ed 134MB][Ee 134MB]
  float* svbv = (float*)d_ws;
  float* Ed = (float*)((char*)d_ws + 256);
  float* Ee = Ed + (size_t)NB * NT * NU;

  hipLaunchKernelGGL(k_sumv, dim3(1), dim3(256), 0, stream, V, bV, svbv);
  hipLaunchKernelGGL(k_proj_exp, dim3(NU / 128, (NB * NT) / 128), dim3(256), 0, stream,
                     dec_outputs, W1, b1, Ed);
  hipLaunchKernelGGL(k_proj_exp, dim3(NU / 128, (NB * NL) / 128), dim3(256), 0, stream,
                     enc_outputs, W2, b2, Ee);
  hipLaunchKernelGGL(k_score, dim3(NL / 32, NT / 32, NB), dim3(64), 0, stream,
                     Ed, Ee, V, svbv, out);
  hipLaunchKernelGGL(k_seq, dim3(NB), dim3(64), 0, stream, out);
}

// Round 8
// 3002.420 us; speedup vs baseline: 6.9617x; 3.5794x over previous
//
#include <hip/hip_runtime.h>
#include <cstdint>

#define NB 128
#define NT 512
#define NL 512
#define NH 512
#define NU 512

// 2*log2(e): tanh(x) = 1 - 2/(exp2(K2E*x)+1); exp2 hoisted into the GEMM epilogue.
static constexpr float K2E = 2.8853900817779268f;

// ---------------------------------------------------------------- K0: sum(V)+bV
__global__ __launch_bounds__(256) void k_sumv(const float* __restrict__ V,
                                              const float* __restrict__ bV,
                                              float* __restrict__ svbv) {
  __shared__ float red[256];
  int tid = threadIdx.x;
  red[tid] = V[tid] + V[tid + 256];
  __syncthreads();
  for (int off = 128; off > 0; off >>= 1) {
    if (tid < off) red[tid] += red[tid + off];
    __syncthreads();
  }
  if (tid == 0) svbv[0] = red[0] + bV[0];
}

// --------------------------------------- K1/K2: out = exp2(K2E*(A@W + bias))
__global__ __launch_bounds__(256) void k_proj_exp(const float* __restrict__ A,
                                                  const float* __restrict__ W,
                                                  const float* __restrict__ bias,
                                                  float* __restrict__ out) {
  __shared__ float As[128 * 32];   // swizzled 16B granules, row stride 128B
  __shared__ float Ws[32 * 132];   // padded stride 132 floats
  const int tid = threadIdx.x;
  const int m0 = blockIdx.y * 128;
  const int n0 = blockIdx.x * 128;
  const int i = tid & 15;
  const int j = tid >> 4;
  const int ga = tid & 7, mra = tid >> 3;
  const int gw = tid & 31, kw = tid >> 5;

  float acc[8][8];
#pragma unroll
  for (int a = 0; a < 8; ++a)
#pragma unroll
    for (int b = 0; b < 8; ++b) acc[a][b] = 0.f;

  for (int kc = 0; kc < NH; kc += 32) {
#pragma unroll
    for (int q = 0; q < 4; ++q) {
      int row = mra + 32 * q;
      float4 av = *(const float4*)(A + (size_t)(m0 + row) * NH + kc + 4 * ga);
      int pos = ga ^ ((row ^ (row >> 3)) & 7);
      *(float4*)(As + row * 32 + 4 * pos) = av;
    }
#pragma unroll
    for (int q = 0; q < 4; ++q) {
      int row = kw + 8 * q;
      float4 wv = *(const float4*)(W + (size_t)(kc + row) * NU + n0 + 4 * gw);
      *(float4*)(Ws + row * 132 + 4 * gw) = wv;
    }
    __syncthreads();
#pragma unroll
    for (int k4 = 0; k4 < 32; k4 += 4) {
      const int gk = k4 >> 2;
      float4 a4[8];
      float4 bl[4], bh[4];
#pragma unroll
      for (int r = 0; r < 8; ++r) {
        int row = 8 * i + r;
        a4[r] = *(const float4*)(As + row * 32 + 4 * (gk ^ ((row ^ (row >> 3)) & 7)));
      }
#pragma unroll
      for (int r = 0; r < 4; ++r) {
        bl[r] = *(const float4*)(Ws + (k4 + r) * 132 + 8 * j);
        bh[r] = *(const float4*)(Ws + (k4 + r) * 132 + 8 * j + 4);
      }
#pragma unroll
      for (int r = 0; r < 4; ++r) {
        float bv[8] = {bl[r].x, bl[r].y, bl[r].z, bl[r].w,
                       bh[r].x, bh[r].y, bh[r].z, bh[r].w};
#pragma unroll
        for (int a = 0; a < 8; ++a) {
          float av = ((const float*)&a4[a])[r];
#pragma unroll
          for (int b = 0; b < 8; ++b) acc[a][b] = fmaf(av, bv[b], acc[a][b]);
        }
      }
    }
    __syncthreads();
  }
#pragma unroll
  for (int a = 0; a < 8; ++a) {
    size_t orow = (size_t)(m0 + 8 * i + a) * NU + n0 + 8 * j;
#pragma unroll
    for (int b = 0; b < 8; b += 4) {
      float4 ov;
      ov.x = __builtin_amdgcn_exp2f(K2E * (acc[a][b + 0] + bias[n0 + 8 * j + b + 0]));
      ov.y = __builtin_amdgcn_exp2f(K2E * (acc[a][b + 1] + bias[n0 + 8 * j + b + 1]));
      ov.z = __builtin_amdgcn_exp2f(K2E * (acc[a][b + 2] + bias[n0 + 8 * j + b + 2]));
      ov.w = __builtin_amdgcn_exp2f(K2E * (acc[a][b + 3] + bias[n0 + 8 * j + b + 3]));
      *(float4*)(out + orow + b) = ov;
    }
  }
}

// ---------------------------------------------- K3: S[b,t,l] = base - 2*sum_u V*rc
// R5 shell (256 thr, 64x64 tile, dbuf LDS, 1 uniform barrier/chunk) with a
// register-lean inner loop: quad fraction tree (14 VALU + 1 rcp / 4 elems),
// b4[4] per g4 + one a4 row at a time, g4 loop NOT unrolled. Target: natural
// VGPR <= 128 -> 4 waves/SIMD. NO launch_bounds occupancy arg (R6/R7 burns).
__global__ __launch_bounds__(256) void k_score(const float* __restrict__ Ed,
                                               const float* __restrict__ Ee,
                                               const float* __restrict__ Vv,
                                               const float* __restrict__ svbv,
                                               float* __restrict__ out) {
  __shared__ float dpl[2][64 * 32];   // 2 x 8 KB, swizzled 16B granules
  __shared__ float epl[2][64 * 32];   // 2 x 8 KB
  const int tid = threadIdx.x;
  const int b = blockIdx.z;
  const int t0 = blockIdx.y * 64;
  const int l0 = blockIdx.x * 64;
  const int ti = tid & 15;          // t micro group (4 rows)
  const int lj = tid >> 4;          // l micro group (4 cols)
  const int tt = tid & 63;          // staging row
  const int g0 = (tid >> 6) * 2;    // staging granules g0, g0+1
  const float* Edb = Ed + ((size_t)b * NT + t0) * NU;
  const float* Eeb = Ee + ((size_t)b * NL + l0) * NU;
  const int sw = (tt ^ (tt >> 3)) & 7;
  const int pos0 = tt * 32 + 4 * ((g0 + 0) ^ sw);
  const int pos1 = tt * 32 + 4 * ((g0 + 1) ^ sw);
  const size_t srow = (size_t)tt * NU;

  float acc[4][4];
#pragma unroll
  for (int a = 0; a < 4; ++a)
#pragma unroll
    for (int c = 0; c < 4; ++c) acc[a][c] = 0.f;

  // prologue: stage chunk 0 into buffer 0
  {
    float4 d0 = *(const float4*)(Edb + srow + 4 * g0);
    float4 d1 = *(const float4*)(Edb + srow + 4 * g0 + 4);
    float4 e0 = *(const float4*)(Eeb + srow + 4 * g0);
    float4 e1 = *(const float4*)(Eeb + srow + 4 * g0 + 4);
    *(float4*)(dpl[0] + pos0) = d0;
    *(float4*)(dpl[0] + pos1) = d1;
    *(float4*)(epl[0] + pos0) = e0;
    *(float4*)(epl[0] + pos1) = e1;
  }
  __syncthreads();

#pragma unroll 1
  for (int c = 0; c < 16; ++c) {
    const int cur = c & 1;
    // issue next-chunk global loads first (latency hidden under compute)
    float4 pd0, pd1, pe0, pe1;
    if (c < 15) {
      const int uc = (c + 1) * 32;
      pd0 = *(const float4*)(Edb + srow + uc + 4 * g0);
      pd1 = *(const float4*)(Edb + srow + uc + 4 * g0 + 4);
      pe0 = *(const float4*)(Eeb + srow + uc + 4 * g0);
      pe1 = *(const float4*)(Eeb + srow + uc + 4 * g0 + 4);
    }
    const float* dbuf = dpl[cur];
    const float* ebuf = epl[cur];
#pragma unroll 1
    for (int g4 = 0; g4 < 8; ++g4) {
      // wave-uniform V loads -> scalar (SGPR) operands
      const float* vb = Vv + c * 32 + g4 * 4;
      const float v0 = vb[0], v1 = vb[1], v2 = vb[2], v3 = vb[3];
      float4 b4[4];
#pragma unroll
      for (int r = 0; r < 4; ++r) {
        int rowb = 4 * lj + r;
        b4[r] = *(const float4*)(ebuf + rowb * 32 + 4 * (g4 ^ ((rowb ^ (rowb >> 3)) & 7)));
      }
#pragma unroll
      for (int a = 0; a < 4; ++a) {
        int rowa = 4 * ti + a;
        float4 a4 = *(const float4*)(dbuf + rowa * 32 + 4 * (g4 ^ ((rowa ^ (rowa >> 3)) & 7)));
#pragma unroll
        for (int cc = 0; cc < 4; ++cc) {
          const float* bp = (const float*)&b4[cc];
          float d0 = fmaf(a4.x, bp[0], 1.0f);
          float d1 = fmaf(a4.y, bp[1], 1.0f);
          float d2 = fmaf(a4.z, bp[2], 1.0f);
          float d3 = fmaf(a4.w, bp[3], 1.0f);
          float d01 = d0 * d1;
          float d23 = d2 * d3;
          float n01 = fmaf(v0, d1, v1 * d0);
          float n23 = fmaf(v2, d3, v3 * d2);
          float num = fmaf(n01, d23, n23 * d01);
          float den = d01 * d23;
          acc[a][cc] = fmaf(num, __builtin_amdgcn_rcpf(den), acc[a][cc]);
        }
      }
    }
    // write next chunk into the other buffer, then one (uniform) barrier
    if (c < 15) {
      float* dn = dpl[cur ^ 1];
      float* en = epl[cur ^ 1];
      *(float4*)(dn + pos0) = pd0;
      *(float4*)(dn + pos1) = pd1;
      *(float4*)(en + pos0) = pe0;
      *(float4*)(en + pos1) = pe1;
    }
    __syncthreads();
  }

  const float base = svbv[0];  // sum(V) + bV
#pragma unroll
  for (int a = 0; a < 4; ++a) {
    size_t orow = ((size_t)b * NT + t0 + 4 * ti + a) * NL + l0 + 4 * lj;
    float4 ov;
    ov.x = base - 2.f * acc[a][0];
    ov.y = base - 2.f * acc[a][1];
    ov.z = base - 2.f * acc[a][2];
    ov.w = base - 2.f * acc[a][3];
    *(float4*)(out + orow) = ov;
  }
}

// ------------------------- K4: sequential mask/softmax/argmax, in-place on d_out
__global__ __launch_bounds__(64) void k_seq(float* __restrict__ out) {
  const int b = blockIdx.x;
  const int lane = threadIdx.x;
  float* base = out + (size_t)b * NT * NL;
  float maskf[8];
#pragma unroll
  for (int k = 0; k < 8; ++k) maskf[k] = 0.f;
  float cur[8];
#pragma unroll
  for (int k = 0; k < 8; ++k) cur[k] = base[lane + 64 * k];

  for (int t = 0; t < NT; ++t) {
    float nxt[8] = {0.f, 0.f, 0.f, 0.f, 0.f, 0.f, 0.f, 0.f};
    if (t + 1 < NT) {
      const float* nr = base + (size_t)(t + 1) * NL;
#pragma unroll
      for (int k = 0; k < 8; ++k) nxt[k] = nr[lane + 64 * k];
    }
    float v[8];
    float mval = -3.4e38f;
    int midx = 0x7fffffff;
#pragma unroll
    for (int k = 0; k < 8; ++k) {
      v[k] = cur[k] - maskf[k] * 1000000.0f;
      int idx = lane + 64 * k;
      if (v[k] > mval || (v[k] == mval && idx < midx)) { mval = v[k]; midx = idx; }
    }
#pragma unroll
    for (int off = 32; off > 0; off >>= 1) {
      float ov = __shfl_xor(mval, off);
      int oi = __shfl_xor(midx, off);
      if (ov > mval || (ov == mval && oi < midx)) { mval = ov; midx = oi; }
    }
    float p[8];
    float psum = 0.f;
#pragma unroll
    for (int k = 0; k < 8; ++k) { p[k] = __expf(v[k] - mval); psum += p[k]; }
#pragma unroll
    for (int off = 32; off > 0; off >>= 1) psum += __shfl_xor(psum, off);
    const float inv = 1.0f / psum;
    float* orow = base + (size_t)t * NL;
#pragma unroll
    for (int k = 0; k < 8; ++k) orow[lane + 64 * k] = p[k] * inv;
#pragma unroll
    for (int k = 0; k < 8; ++k)
      if (lane + 64 * k == midx) maskf[k] += 1.0f;
#pragma unroll
    for (int k = 0; k < 8; ++k) cur[k] = nxt[k];
  }
}

extern "C" void kernel_launch(void* const* d_in, const int* in_sizes, int n_in,
                              void* d_out, int out_size, void* d_ws, size_t ws_size,
                              hipStream_t stream) {
  const float* dec_outputs = (const float*)d_in[0];  // [B,T,H]
  const float* enc_outputs = (const float*)d_in[1];  // [B,L,H]
  const float* W1 = (const float*)d_in[3];
  const float* b1 = (const float*)d_in[4];
  const float* W2 = (const float*)d_in[5];
  const float* b2 = (const float*)d_in[6];
  const float* V  = (const float*)d_in[7];
  const float* bV = (const float*)d_in[8];
  float* out = (float*)d_out;  // [B,T,L] f32

  // workspace: [svbv pad 256B][Ed 134MB][Ee 134MB]
  float* svbv = (float*)d_ws;
  float* Ed = (float*)((char*)d_ws + 256);
  float* Ee = Ed + (size_t)NB * NT * NU;

  hipLaunchKernelGGL(k_sumv, dim3(1), dim3(256), 0, stream, V, bV, svbv);
  hipLaunchKernelGGL(k_proj_exp, dim3(NU / 128, (NB * NT) / 128), dim3(256), 0, stream,
                     dec_outputs, W1, b1, Ed);
  hipLaunchKernelGGL(k_proj_exp, dim3(NU / 128, (NB * NL) / 128), dim3(256), 0, stream,
                     enc_outputs, W2, b2, Ee);
  hipLaunchKernelGGL(k_score, dim3(NL / 64, NT / 64, NB), dim3(256), 0, stream,
                     Ed, Ee, V, svbv, out);
  hipLaunchKernelGGL(k_seq, dim3(NB), dim3(64), 0, stream, out);
}

// Round 9
// 2841.876 us; speedup vs baseline: 7.3550x; 1.0565x over previous
//
#include <hip/hip_runtime.h>
#include <cstdint>

#define NB 128
#define NT 512
#define NL 512
#define NH 512
#define NU 512

// 2*log2(e): tanh(x) = 1 - 2/(exp2(K2E*x)+1); exp2 hoisted into the GEMM epilogue.
static constexpr float K2E = 2.8853900817779268f;

// ---------------------------------------------------------------- K0: sum(V)+bV
__global__ __launch_bounds__(256) void k_sumv(const float* __restrict__ V,
                                              const float* __restrict__ bV,
                                              float* __restrict__ svbv) {
  __shared__ float red[256];
  int tid = threadIdx.x;
  red[tid] = V[tid] + V[tid + 256];
  __syncthreads();
  for (int off = 128; off > 0; off >>= 1) {
    if (tid < off) red[tid] += red[tid + off];
    __syncthreads();
  }
  if (tid == 0) svbv[0] = red[0] + bV[0];
}

// --------------------------------------- K1/K2: out = exp2(K2E*(A@W + bias))
__global__ __launch_bounds__(256) void k_proj_exp(const float* __restrict__ A,
                                                  const float* __restrict__ W,
                                                  const float* __restrict__ bias,
                                                  float* __restrict__ out) {
  __shared__ float As[128 * 32];   // swizzled 16B granules, row stride 128B
  __shared__ float Ws[32 * 132];   // padded stride 132 floats
  const int tid = threadIdx.x;
  const int m0 = blockIdx.y * 128;
  const int n0 = blockIdx.x * 128;
  const int i = tid & 15;
  const int j = tid >> 4;
  const int ga = tid & 7, mra = tid >> 3;
  const int gw = tid & 31, kw = tid >> 5;

  float acc[8][8];
#pragma unroll
  for (int a = 0; a < 8; ++a)
#pragma unroll
    for (int b = 0; b < 8; ++b) acc[a][b] = 0.f;

  for (int kc = 0; kc < NH; kc += 32) {
#pragma unroll
    for (int q = 0; q < 4; ++q) {
      int row = mra + 32 * q;
      float4 av = *(const float4*)(A + (size_t)(m0 + row) * NH + kc + 4 * ga);
      int pos = ga ^ ((row ^ (row >> 3)) & 7);
      *(float4*)(As + row * 32 + 4 * pos) = av;
    }
#pragma unroll
    for (int q = 0; q < 4; ++q) {
      int row = kw + 8 * q;
      float4 wv = *(const float4*)(W + (size_t)(kc + row) * NU + n0 + 4 * gw);
      *(float4*)(Ws + row * 132 + 4 * gw) = wv;
    }
    __syncthreads();
#pragma unroll
    for (int k4 = 0; k4 < 32; k4 += 4) {
      const int gk = k4 >> 2;
      float4 a4[8];
      float4 bl[4], bh[4];
#pragma unroll
      for (int r = 0; r < 8; ++r) {
        int row = 8 * i + r;
        a4[r] = *(const float4*)(As + row * 32 + 4 * (gk ^ ((row ^ (row >> 3)) & 7)));
      }
#pragma unroll
      for (int r = 0; r < 4; ++r) {
        bl[r] = *(const float4*)(Ws + (k4 + r) * 132 + 8 * j);
        bh[r] = *(const float4*)(Ws + (k4 + r) * 132 + 8 * j + 4);
      }
#pragma unroll
      for (int r = 0; r < 4; ++r) {
        float bv[8] = {bl[r].x, bl[r].y, bl[r].z, bl[r].w,
                       bh[r].x, bh[r].y, bh[r].z, bh[r].w};
#pragma unroll
        for (int a = 0; a < 8; ++a) {
          float av = ((const float*)&a4[a])[r];
#pragma unroll
          for (int b = 0; b < 8; ++b) acc[a][b] = fmaf(av, bv[b], acc[a][b]);
        }
      }
    }
    __syncthreads();
  }
#pragma unroll
  for (int a = 0; a < 8; ++a) {
    size_t orow = (size_t)(m0 + 8 * i + a) * NU + n0 + 8 * j;
#pragma unroll
    for (int b = 0; b < 8; b += 4) {
      float4 ov;
      ov.x = __builtin_amdgcn_exp2f(K2E * (acc[a][b + 0] + bias[n0 + 8 * j + b + 0]));
      ov.y = __builtin_amdgcn_exp2f(K2E * (acc[a][b + 1] + bias[n0 + 8 * j + b + 1]));
      ov.z = __builtin_amdgcn_exp2f(K2E * (acc[a][b + 2] + bias[n0 + 8 * j + b + 2]));
      ov.w = __builtin_amdgcn_exp2f(K2E * (acc[a][b + 3] + bias[n0 + 8 * j + b + 3]));
      *(float4*)(out + orow + b) = ov;
    }
  }
}

// ---------------------------------------------- K3: S[b,t,l] = base - 2*sum_u V*rc
// R8 lean shell (256 thr, 64x64 tile, dbuf LDS, 1 uniform barrier/chunk) with the
// octet fraction tree (29 VALU + acc-fma + 1 rcp per 8 elems, R4/R5-proven math):
// issue/elem ~10.6 cy vs quad's 14.7. Loads stay lean: b as 4x2 float4 per g8,
// one a-row (2 float4) at a time; g8 loop NOT unrolled -> live set ~105 VGPR.
__global__ __launch_bounds__(256) void k_score(const float* __restrict__ Ed,
                                               const float* __restrict__ Ee,
                                               const float* __restrict__ Vv,
                                               const float* __restrict__ svbv,
                                               float* __restrict__ out) {
  __shared__ float dpl[2][64 * 32];   // 2 x 8 KB, swizzled 16B granules
  __shared__ float epl[2][64 * 32];   // 2 x 8 KB
  const int tid = threadIdx.x;
  const int b = blockIdx.z;
  const int t0 = blockIdx.y * 64;
  const int l0 = blockIdx.x * 64;
  const int ti = tid & 15;          // t micro group (4 rows)
  const int lj = tid >> 4;          // l micro group (4 cols)
  const int tt = tid & 63;          // staging row
  const int g0 = (tid >> 6) * 2;    // staging granules g0, g0+1
  const float* Edb = Ed + ((size_t)b * NT + t0) * NU;
  const float* Eeb = Ee + ((size_t)b * NL + l0) * NU;
  const int sw = (tt ^ (tt >> 3)) & 7;
  const int pos0 = tt * 32 + 4 * ((g0 + 0) ^ sw);
  const int pos1 = tt * 32 + 4 * ((g0 + 1) ^ sw);
  const size_t srow = (size_t)tt * NU;

  float acc[4][4];
#pragma unroll
  for (int a = 0; a < 4; ++a)
#pragma unroll
    for (int c = 0; c < 4; ++c) acc[a][c] = 0.f;

  // prologue: stage chunk 0 into buffer 0
  {
    float4 d0 = *(const float4*)(Edb + srow + 4 * g0);
    float4 d1 = *(const float4*)(Edb + srow + 4 * g0 + 4);
    float4 e0 = *(const float4*)(Eeb + srow + 4 * g0);
    float4 e1 = *(const float4*)(Eeb + srow + 4 * g0 + 4);
    *(float4*)(dpl[0] + pos0) = d0;
    *(float4*)(dpl[0] + pos1) = d1;
    *(float4*)(epl[0] + pos0) = e0;
    *(float4*)(epl[0] + pos1) = e1;
  }
  __syncthreads();

#pragma unroll 1
  for (int c = 0; c < 16; ++c) {
    const int cur = c & 1;
    // issue next-chunk global loads first (latency hidden under compute)
    float4 pd0, pd1, pe0, pe1;
    if (c < 15) {
      const int uc = (c + 1) * 32;
      pd0 = *(const float4*)(Edb + srow + uc + 4 * g0);
      pd1 = *(const float4*)(Edb + srow + uc + 4 * g0 + 4);
      pe0 = *(const float4*)(Eeb + srow + uc + 4 * g0);
      pe1 = *(const float4*)(Eeb + srow + uc + 4 * g0 + 4);
    }
    const float* dbuf = dpl[cur];
    const float* ebuf = epl[cur];
#pragma unroll 1
    for (int g8 = 0; g8 < 4; ++g8) {
      // wave-uniform V loads -> scalar (SGPR) operands
      const float* vb = Vv + c * 32 + g8 * 8;
      const float v0 = vb[0], v1 = vb[1], v2 = vb[2], v3 = vb[3];
      const float v4_ = vb[4], v5 = vb[5], v6 = vb[6], v7 = vb[7];
      float4 bLo[4], bHi[4];
#pragma unroll
      for (int r = 0; r < 4; ++r) {
        int rowb = 4 * lj + r;
        int swb = (rowb ^ (rowb >> 3)) & 7;
        bLo[r] = *(const float4*)(ebuf + rowb * 32 + 4 * ((2 * g8 + 0) ^ swb));
        bHi[r] = *(const float4*)(ebuf + rowb * 32 + 4 * ((2 * g8 + 1) ^ swb));
      }
#pragma unroll
      for (int a = 0; a < 4; ++a) {
        int rowa = 4 * ti + a;
        int swa = (rowa ^ (rowa >> 3)) & 7;
        float4 aLo = *(const float4*)(dbuf + rowa * 32 + 4 * ((2 * g8 + 0) ^ swa));
        float4 aHi = *(const float4*)(dbuf + rowa * 32 + 4 * ((2 * g8 + 1) ^ swa));
#pragma unroll
        for (int cc = 0; cc < 4; ++cc) {
          const float* bp = (const float*)&bLo[cc];
          const float* bh = (const float*)&bHi[cc];
          float d0 = fmaf(aLo.x, bp[0], 1.0f);
          float d1 = fmaf(aLo.y, bp[1], 1.0f);
          float d2 = fmaf(aLo.z, bp[2], 1.0f);
          float d3 = fmaf(aLo.w, bp[3], 1.0f);
          float d4 = fmaf(aHi.x, bh[0], 1.0f);
          float d5 = fmaf(aHi.y, bh[1], 1.0f);
          float d6 = fmaf(aHi.z, bh[2], 1.0f);
          float d7 = fmaf(aHi.w, bh[3], 1.0f);
          float d01 = d0 * d1, d23 = d2 * d3, d45 = d4 * d5, d67 = d6 * d7;
          float n01 = fmaf(v0, d1, v1 * d0);
          float n23 = fmaf(v2, d3, v3 * d2);
          float n45 = fmaf(v4_, d5, v5 * d4);
          float n67 = fmaf(v6, d7, v7 * d6);
          float n03 = fmaf(n01, d23, n23 * d01);
          float d03 = d01 * d23;
          float n47 = fmaf(n45, d67, n67 * d45);
          float d47 = d45 * d67;
          float num = fmaf(n03, d47, n47 * d03);
          float den = d03 * d47;
          acc[a][cc] = fmaf(num, __builtin_amdgcn_rcpf(den), acc[a][cc]);
        }
      }
    }
    // write next chunk into the other buffer, then one (uniform) barrier
    if (c < 15) {
      float* dn = dpl[cur ^ 1];
      float* en = epl[cur ^ 1];
      *(float4*)(dn + pos0) = pd0;
      *(float4*)(dn + pos1) = pd1;
      *(float4*)(en + pos0) = pe0;
      *(float4*)(en + pos1) = pe1;
    }
    __syncthreads();
  }

  const float base = svbv[0];  // sum(V) + bV
#pragma unroll
  for (int a = 0; a < 4; ++a) {
    size_t orow = ((size_t)b * NT + t0 + 4 * ti + a) * NL + l0 + 4 * lj;
    float4 ov;
    ov.x = base - 2.f * acc[a][0];
    ov.y = base - 2.f * acc[a][1];
    ov.z = base - 2.f * acc[a][2];
    ov.w = base - 2.f * acc[a][3];
    *(float4*)(out + orow) = ov;
  }
}

// ------------------------- K4: sequential mask/softmax/argmax, in-place on d_out
__global__ __launch_bounds__(64) void k_seq(float* __restrict__ out) {
  const int b = blockIdx.x;
  const int lane = threadIdx.x;
  float* base = out + (size_t)b * NT * NL;
  float maskf[8];
#pragma unroll
  for (int k = 0; k < 8; ++k) maskf[k] = 0.f;
  float cur[8];
#pragma unroll
  for (int k = 0; k < 8; ++k) cur[k] = base[lane + 64 * k];

  for (int t = 0; t < NT; ++t) {
    float nxt[8] = {0.f, 0.f, 0.f, 0.f, 0.f, 0.f, 0.f, 0.f};
    if (t + 1 < NT) {
      const float* nr = base + (size_t)(t + 1) * NL;
#pragma unroll
      for (int k = 0; k < 8; ++k) nxt[k] = nr[lane + 64 * k];
    }
    float v[8];
    float mval = -3.4e38f;
    int midx = 0x7fffffff;
#pragma unroll
    for (int k = 0; k < 8; ++k) {
      v[k] = cur[k] - maskf[k] * 1000000.0f;
      int idx = lane + 64 * k;
      if (v[k] > mval || (v[k] == mval && idx < midx)) { mval = v[k]; midx = idx; }
    }
#pragma unroll
    for (int off = 32; off > 0; off >>= 1) {
      float ov = __shfl_xor(mval, off);
      int oi = __shfl_xor(midx, off);
      if (ov > mval || (ov == mval && oi < midx)) { mval = ov; midx = oi; }
    }
    float p[8];
    float psum = 0.f;
#pragma unroll
    for (int k = 0; k < 8; ++k) { p[k] = __expf(v[k] - mval); psum += p[k]; }
#pragma unroll
    for (int off = 32; off > 0; off >>= 1) psum += __shfl_xor(psum, off);
    const float inv = 1.0f / psum;
    float* orow = base + (size_t)t * NL;
#pragma unroll
    for (int k = 0; k < 8; ++k) orow[lane + 64 * k] = p[k] * inv;
#pragma unroll
    for (int k = 0; k < 8; ++k)
      if (lane + 64 * k == midx) maskf[k] += 1.0f;
#pragma unroll
    for (int k = 0; k < 8; ++k) cur[k] = nxt[k];
  }
}

extern "C" void kernel_launch(void* const* d_in, const int* in_sizes, int n_in,
                              void* d_out, int out_size, void* d_ws, size_t ws_size,
                              hipStream_t stream) {
  const float* dec_outputs = (const float*)d_in[0];  // [B,T,H]
  const float* enc_outputs = (const float*)d_in[1];  // [B,L,H]
  const float* W1 = (const float*)d_in[3];
  const float* b1 = (const float*)d_in[4];
  const float* W2 = (const float*)d_in[5];
  const float* b2 = (const float*)d_in[6];
  const float* V  = (const float*)d_in[7];
  const float* bV = (const float*)d_in[8];
  float* out = (float*)d_out;  // [B,T,L] f32

  // workspace: [svbv pad 256B][Ed 134MB][Ee 134MB]
  float* svbv = (float*)d_ws;
  float* Ed = (float*)((char*)d_ws + 256);
  float* Ee = Ed + (size_t)NB * NT * NU;

  hipLaunchKernelGGL(k_sumv, dim3(1), dim3(256), 0, stream, V, bV, svbv);
  hipLaunchKernelGGL(k_proj_exp, dim3(NU / 128, (NB * NT) / 128), dim3(256), 0, stream,
                     dec_outputs, W1, b1, Ed);
  hipLaunchKernelGGL(k_proj_exp, dim3(NU / 128, (NB * NL) / 128), dim3(256), 0, stream,
                     enc_outputs, W2, b2, Ee);
  hipLaunchKernelGGL(k_score, dim3(NL / 64, NT / 64, NB), dim3(256), 0, stream,
                     Ed, Ee, V, svbv, out);
  hipLaunchKernelGGL(k_seq, dim3(NB), dim3(64), 0, stream, out);
}

// Round 10
// 2696.533 us; speedup vs baseline: 7.7514x; 1.0539x over previous
//
#include <hip/hip_runtime.h>
#include <cstdint>

#define NB 128
#define NT 512
#define NL 512
#define NH 512
#define NU 512

// 2*log2(e): tanh(x) = 1 - 2/(exp2(K2E*x)+1); exp2 hoisted into the GEMM epilogue.
static constexpr float K2E = 2.8853900817779268f;

// ---------------------------------------------------------------- K0: sum(V)+bV
__global__ __launch_bounds__(256) void k_sumv(const float* __restrict__ V,
                                              const float* __restrict__ bV,
                                              float* __restrict__ svbv) {
  __shared__ float red[256];
  int tid = threadIdx.x;
  red[tid] = V[tid] + V[tid + 256];
  __syncthreads();
  for (int off = 128; off > 0; off >>= 1) {
    if (tid < off) red[tid] += red[tid + off];
    __syncthreads();
  }
  if (tid == 0) svbv[0] = red[0] + bV[0];
}

// --------------------------------------- K1/K2: out = exp2(K2E*(A@W + bias))
__global__ __launch_bounds__(256) void k_proj_exp(const float* __restrict__ A,
                                                  const float* __restrict__ W,
                                                  const float* __restrict__ bias,
                                                  float* __restrict__ out) {
  __shared__ float As[128 * 32];   // swizzled 16B granules, row stride 128B
  __shared__ float Ws[32 * 132];   // padded stride 132 floats
  const int tid = threadIdx.x;
  const int m0 = blockIdx.y * 128;
  const int n0 = blockIdx.x * 128;
  const int i = tid & 15;
  const int j = tid >> 4;
  const int ga = tid & 7, mra = tid >> 3;
  const int gw = tid & 31, kw = tid >> 5;

  float acc[8][8];
#pragma unroll
  for (int a = 0; a < 8; ++a)
#pragma unroll
    for (int b = 0; b < 8; ++b) acc[a][b] = 0.f;

  for (int kc = 0; kc < NH; kc += 32) {
#pragma unroll
    for (int q = 0; q < 4; ++q) {
      int row = mra + 32 * q;
      float4 av = *(const float4*)(A + (size_t)(m0 + row) * NH + kc + 4 * ga);
      int pos = ga ^ ((row ^ (row >> 3)) & 7);
      *(float4*)(As + row * 32 + 4 * pos) = av;
    }
#pragma unroll
    for (int q = 0; q < 4; ++q) {
      int row = kw + 8 * q;
      float4 wv = *(const float4*)(W + (size_t)(kc + row) * NU + n0 + 4 * gw);
      *(float4*)(Ws + row * 132 + 4 * gw) = wv;
    }
    __syncthreads();
#pragma unroll
    for (int k4 = 0; k4 < 32; k4 += 4) {
      const int gk = k4 >> 2;
      float4 a4[8];
      float4 bl[4], bh[4];
#pragma unroll
      for (int r = 0; r < 8; ++r) {
        int row = 8 * i + r;
        a4[r] = *(const float4*)(As + row * 32 + 4 * (gk ^ ((row ^ (row >> 3)) & 7)));
      }
#pragma unroll
      for (int r = 0; r < 4; ++r) {
        bl[r] = *(const float4*)(Ws + (k4 + r) * 132 + 8 * j);
        bh[r] = *(const float4*)(Ws + (k4 + r) * 132 + 8 * j + 4);
      }
#pragma unroll
      for (int r = 0; r < 4; ++r) {
        float bv[8] = {bl[r].x, bl[r].y, bl[r].z, bl[r].w,
                       bh[r].x, bh[r].y, bh[r].z, bh[r].w};
#pragma unroll
        for (int a = 0; a < 8; ++a) {
          float av = ((const float*)&a4[a])[r];
#pragma unroll
          for (int b = 0; b < 8; ++b) acc[a][b] = fmaf(av, bv[b], acc[a][b]);
        }
      }
    }
    __syncthreads();
  }
#pragma unroll
  for (int a = 0; a < 8; ++a) {
    size_t orow = (size_t)(m0 + 8 * i + a) * NU + n0 + 8 * j;
#pragma unroll
    for (int b = 0; b < 8; b += 4) {
      float4 ov;
      ov.x = __builtin_amdgcn_exp2f(K2E * (acc[a][b + 0] + bias[n0 + 8 * j + b + 0]));
      ov.y = __builtin_amdgcn_exp2f(K2E * (acc[a][b + 1] + bias[n0 + 8 * j + b + 1]));
      ov.z = __builtin_amdgcn_exp2f(K2E * (acc[a][b + 2] + bias[n0 + 8 * j + b + 2]));
      ov.w = __builtin_amdgcn_exp2f(K2E * (acc[a][b + 3] + bias[n0 + 8 * j + b + 3]));
      *(float4*)(out + orow + b) = ov;
    }
  }
}

// ---------------------------------------------- K3: S[b,t,l] = base - 2*sum_u V*rc
// R9 octet inner (29 VALU + acc-fma + 1 rcp / 8 elems) on a SINGLE-buffered
// 16.4 KB LDS shell: compute -> barrier -> write-next -> barrier. Halved LDS
// lifts resident blocks/CU 5 -> 7 (VGPR ~72 -> 7 waves/SIMD) to fill convoy
// stalls. Natural register allocation -- NO launch_bounds occupancy arg.
__global__ __launch_bounds__(256) void k_score(const float* __restrict__ Ed,
                                               const float* __restrict__ Ee,
                                               const float* __restrict__ Vv,
                                               const float* __restrict__ svbv,
                                               float* __restrict__ out) {
  __shared__ float dpl[64 * 32];   // 8 KB, swizzled 16B granules
  __shared__ float epl[64 * 32];   // 8 KB
  const int tid = threadIdx.x;
  const int b = blockIdx.z;
  const int t0 = blockIdx.y * 64;
  const int l0 = blockIdx.x * 64;
  const int ti = tid & 15;          // t micro group (4 rows)
  const int lj = tid >> 4;          // l micro group (4 cols)
  const int tt = tid & 63;          // staging row
  const int g0 = (tid >> 6) * 2;    // staging granules g0, g0+1
  const float* Edb = Ed + ((size_t)b * NT + t0) * NU;
  const float* Eeb = Ee + ((size_t)b * NL + l0) * NU;
  const int sw = (tt ^ (tt >> 3)) & 7;
  const int pos0 = tt * 32 + 4 * ((g0 + 0) ^ sw);
  const int pos1 = tt * 32 + 4 * ((g0 + 1) ^ sw);
  const size_t srow = (size_t)tt * NU;

  float acc[4][4];
#pragma unroll
  for (int a = 0; a < 4; ++a)
#pragma unroll
    for (int c = 0; c < 4; ++c) acc[a][c] = 0.f;

  // prologue: stage chunk 0
  {
    float4 d0 = *(const float4*)(Edb + srow + 4 * g0);
    float4 d1 = *(const float4*)(Edb + srow + 4 * g0 + 4);
    float4 e0 = *(const float4*)(Eeb + srow + 4 * g0);
    float4 e1 = *(const float4*)(Eeb + srow + 4 * g0 + 4);
    *(float4*)(dpl + pos0) = d0;
    *(float4*)(dpl + pos1) = d1;
    *(float4*)(epl + pos0) = e0;
    *(float4*)(epl + pos1) = e1;
  }
  __syncthreads();

#pragma unroll 1
  for (int c = 0; c < 16; ++c) {
    // issue next-chunk global loads first (latency hidden under compute)
    float4 pd0, pd1, pe0, pe1;
    if (c < 15) {
      const int uc = (c + 1) * 32;
      pd0 = *(const float4*)(Edb + srow + uc + 4 * g0);
      pd1 = *(const float4*)(Edb + srow + uc + 4 * g0 + 4);
      pe0 = *(const float4*)(Eeb + srow + uc + 4 * g0);
      pe1 = *(const float4*)(Eeb + srow + uc + 4 * g0 + 4);
    }
#pragma unroll 1
    for (int g8 = 0; g8 < 4; ++g8) {
      // wave-uniform V loads -> scalar (SGPR) operands
      const float* vb = Vv + c * 32 + g8 * 8;
      const float v0 = vb[0], v1 = vb[1], v2 = vb[2], v3 = vb[3];
      const float v4_ = vb[4], v5 = vb[5], v6 = vb[6], v7 = vb[7];
      float4 bLo[4], bHi[4];
#pragma unroll
      for (int r = 0; r < 4; ++r) {
        int rowb = 4 * lj + r;
        int swb = (rowb ^ (rowb >> 3)) & 7;
        bLo[r] = *(const float4*)(epl + rowb * 32 + 4 * ((2 * g8 + 0) ^ swb));
        bHi[r] = *(const float4*)(epl + rowb * 32 + 4 * ((2 * g8 + 1) ^ swb));
      }
#pragma unroll
      for (int a = 0; a < 4; ++a) {
        int rowa = 4 * ti + a;
        int swa = (rowa ^ (rowa >> 3)) & 7;
        float4 aLo = *(const float4*)(dpl + rowa * 32 + 4 * ((2 * g8 + 0) ^ swa));
        float4 aHi = *(const float4*)(dpl + rowa * 32 + 4 * ((2 * g8 + 1) ^ swa));
#pragma unroll
        for (int cc = 0; cc < 4; ++cc) {
          const float* bp = (const float*)&bLo[cc];
          const float* bh = (const float*)&bHi[cc];
          float d0 = fmaf(aLo.x, bp[0], 1.0f);
          float d1 = fmaf(aLo.y, bp[1], 1.0f);
          float d2 = fmaf(aLo.z, bp[2], 1.0f);
          float d3 = fmaf(aLo.w, bp[3], 1.0f);
          float d4 = fmaf(aHi.x, bh[0], 1.0f);
          float d5 = fmaf(aHi.y, bh[1], 1.0f);
          float d6 = fmaf(aHi.z, bh[2], 1.0f);
          float d7 = fmaf(aHi.w, bh[3], 1.0f);
          float d01 = d0 * d1, d23 = d2 * d3, d45 = d4 * d5, d67 = d6 * d7;
          float n01 = fmaf(v0, d1, v1 * d0);
          float n23 = fmaf(v2, d3, v3 * d2);
          float n45 = fmaf(v4_, d5, v5 * d4);
          float n67 = fmaf(v6, d7, v7 * d6);
          float n03 = fmaf(n01, d23, n23 * d01);
          float d03 = d01 * d23;
          float n47 = fmaf(n45, d67, n67 * d45);
          float d47 = d45 * d67;
          float num = fmaf(n03, d47, n47 * d03);
          float den = d03 * d47;
          acc[a][cc] = fmaf(num, __builtin_amdgcn_rcpf(den), acc[a][cc]);
        }
      }
    }
    __syncthreads();   // all reads of this chunk done (uniform trip count)
    if (c < 15) {
      *(float4*)(dpl + pos0) = pd0;
      *(float4*)(dpl + pos1) = pd1;
      *(float4*)(epl + pos0) = pe0;
      *(float4*)(epl + pos1) = pe1;
      __syncthreads(); // writes visible (uniform)
    }
  }

  const float base = svbv[0];  // sum(V) + bV
#pragma unroll
  for (int a = 0; a < 4; ++a) {
    size_t orow = ((size_t)b * NT + t0 + 4 * ti + a) * NL + l0 + 4 * lj;
    float4 ov;
    ov.x = base - 2.f * acc[a][0];
    ov.y = base - 2.f * acc[a][1];
    ov.z = base - 2.f * acc[a][2];
    ov.w = base - 2.f * acc[a][3];
    *(float4*)(out + orow) = ov;
  }
}

// ------------------------- K4: sequential mask/softmax/argmax, in-place on d_out
// No max-subtraction: |score| <= sum|V| ~ 18 (e^18 << f32 max); masked entries
// exp(-1e6) = 0 exactly. Argmax chain and sum chain interleaved in one 6-step
// shuffle loop -> serial critical path per step ~halved.
__global__ __launch_bounds__(64) void k_seq(float* __restrict__ out) {
  const int b = blockIdx.x;
  const int lane = threadIdx.x;
  float* base = out + (size_t)b * NT * NL;
  float maskf[8];
#pragma unroll
  for (int k = 0; k < 8; ++k) maskf[k] = 0.f;
  float cur[8];
#pragma unroll
  for (int k = 0; k < 8; ++k) cur[k] = base[lane + 64 * k];

  for (int t = 0; t < NT; ++t) {
    float nxt[8] = {0.f, 0.f, 0.f, 0.f, 0.f, 0.f, 0.f, 0.f};
    if (t + 1 < NT) {
      const float* nr = base + (size_t)(t + 1) * NL;
#pragma unroll
      for (int k = 0; k < 8; ++k) nxt[k] = nr[lane + 64 * k];
    }
    float e[8];
    float psum = 0.f;
    float mval = -3.4e38f;
    int midx = 0x7fffffff;
#pragma unroll
    for (int k = 0; k < 8; ++k) {
      float v = cur[k] - maskf[k] * 1000000.0f;
      e[k] = __expf(v);          // masked -> exp(-1e6) = 0 exactly
      psum += e[k];
      int idx = lane + 64 * k;
      if (v > mval || (v == mval && idx < midx)) { mval = v; midx = idx; }
    }
    // interleaved argmax + sum butterflies (independent chains, ILP overlap)
#pragma unroll
    for (int off = 32; off > 0; off >>= 1) {
      float ov = __shfl_xor(mval, off);
      int oi = __shfl_xor(midx, off);
      float ps = __shfl_xor(psum, off);
      psum += ps;
      if (ov > mval || (ov == mval && oi < midx)) { mval = ov; midx = oi; }
    }
    const float inv = 1.0f / psum;
    float* orow = base + (size_t)t * NL;
#pragma unroll
    for (int k = 0; k < 8; ++k) orow[lane + 64 * k] = e[k] * inv;
#pragma unroll
    for (int k = 0; k < 8; ++k)
      if (lane + 64 * k == midx) maskf[k] += 1.0f;
#pragma unroll
    for (int k = 0; k < 8; ++k) cur[k] = nxt[k];
  }
}

extern "C" void kernel_launch(void* const* d_in, const int* in_sizes, int n_in,
                              void* d_out, int out_size, void* d_ws, size_t ws_size,
                              hipStream_t stream) {
  const float* dec_outputs = (const float*)d_in[0];  // [B,T,H]
  const float* enc_outputs = (const float*)d_in[1];  // [B,L,H]
  const float* W1 = (const float*)d_in[3];
  const float* b1 = (const float*)d_in[4];
  const float* W2 = (const float*)d_in[5];
  const float* b2 = (const float*)d_in[6];
  const float* V  = (const float*)d_in[7];
  const float* bV = (const float*)d_in[8];
  float* out = (float*)d_out;  // [B,T,L] f32

  // workspace: [svbv pad 256B][Ed 134MB][Ee 134MB]
  float* svbv = (float*)d_ws;
  float* Ed = (float*)((char*)d_ws + 256);
  float* Ee = Ed + (size_t)NB * NT * NU;

  hipLaunchKernelGGL(k_sumv, dim3(1), dim3(256), 0, stream, V, bV, svbv);
  hipLaunchKernelGGL(k_proj_exp, dim3(NU / 128, (NB * NT) / 128), dim3(256), 0, stream,
                     dec_outputs, W1, b1, Ed);
  hipLaunchKernelGGL(k_proj_exp, dim3(NU / 128, (NB * NL) / 128), dim3(256), 0, stream,
                     enc_outputs, W2, b2, Ee);
  hipLaunchKernelGGL(k_score, dim3(NL / 64, NT / 64, NB), dim3(256), 0, stream,
                     Ed, Ee, V, svbv, out);
  hipLaunchKernelGGL(k_seq, dim3(NB), dim3(64), 0, stream, out);
}